// Round 6
// baseline (310.145 us; speedup 1.0000x reference)
//
#include <hip/hip_runtime.h>
#include <hip/hip_bf16.h>
#include <stdint.h>

typedef __attribute__((ext_vector_type(8))) short bf16x8;
typedef __attribute__((ext_vector_type(4))) float f32x4;

__device__ __forceinline__ unsigned short f2bf(float f) {
    union { float f; unsigned u; } v; v.f = f;
    unsigned u = v.u;
    u += 0x7fff + ((u >> 16) & 1);   // round-to-nearest-even
    return (unsigned short)(u >> 16);
}

// ---------------------------------------------------------------------------
// prep: blocks [0, nbBin): binner (slot claim per feature).
//       blocks [nbBin, nbBin+nbW): convert W0..W3 fp32 -> bf16 into wsW.
// ---------------------------------------------------------------------------
__global__ __launch_bounds__(256) void prep(
    const int* __restrict__ FI, const int* __restrict__ wptr,
    int* __restrict__ cnt, int* __restrict__ slots,
    const float* __restrict__ W0, const float* __restrict__ W1,
    const float* __restrict__ W2, const float* __restrict__ W3,
    unsigned short* __restrict__ wsW,
    int NF, int HW, int wsz, int nbBin)
{
    int blk = blockIdx.x;
    if (blk < nbBin) {
        int i = blk * 256 + threadIdx.x;
        if (i >= NF) return;
        int Wd = *wptr;
        int b = FI[(size_t)i * 3];
        int h = FI[(size_t)i * 3 + 1];
        int w = FI[(size_t)i * 3 + 2];
        int gc = b * HW + h * Wd + w;
        int slot = atomicAdd(&cnt[gc], 1);
        if (slot < 16) slots[(size_t)gc * 16 + slot] = i;
    } else {
        int idx = ((blk - nbBin) * 256 + threadIdx.x) * 4;
        if (idx >= 4 * wsz) return;
        int l = idx / wsz, off = idx - l * wsz;
        const float* Ws = (l == 0) ? W0 : (l == 1) ? W1 : (l == 2) ? W2 : W3;
        float4 v = *(const float4*)(Ws + off);
        ushort4 o; o.x = f2bf(v.x); o.y = f2bf(v.y); o.z = f2bf(v.z); o.w = f2bf(v.w);
        *(ushort4*)(wsW + (size_t)l * wsz + off) = o;
    }
}

// ---------------------------------------------------------------------------
// gather_mlp: blocks [0, nbM): fused 4-layer MLP.
//             blocks [nbM, nbM+nbG): cell gather, HALF-WAVE per cell.
// (round-4 verified version, reverted from the round-5 16-cell variant)
//   - lane hl owns cols {hl*4..+3} and {128+hl*4..+3} of its cell
//   - FV loads: float4, 16B lane stride -> 512B contiguous per instruction
//   - Abuf stores: ushort4, 8B lane stride -> 256B full-line per instruction
//   - loop bound nmax is WAVE-UNIFORM so every __shfl has all 64 lanes active
// ---------------------------------------------------------------------------
__global__ __launch_bounds__(256) void gather_mlp(
    // mlp args
    const float* __restrict__ Qf, const unsigned short* __restrict__ Wb,
    const float* __restrict__ b0p, const float* __restrict__ b1p,
    const float* __restrict__ b2p, const float* __restrict__ b3p,
    unsigned short* __restrict__ outQB, int M, int wsz,
    // gather args
    const float* __restrict__ FV, const int* __restrict__ cnt,
    const int* __restrict__ slots, unsigned short* __restrict__ Abuf, int NC,
    int nbM, int nbG)
{
    __shared__ unsigned short At[16 * 264];
    const int tid = threadIdx.x;
    const int wid = tid >> 6, lane = tid & 63, quad = lane >> 4, l16 = lane & 15;

    if (blockIdx.x >= nbM) {
        // ------------- gather: half-wave per cell, 4 cells per wave -------------
        const int hl  = lane & 31;      // half-lane
        const int hid = lane >> 5;      // which half of the wave
        const int wg = (blockIdx.x - nbM) * 4 + wid;
        const int nw = nbG * 4;
        for (int cb = wg * 4; cb < NC; cb += nw * 4) {
            int sl = slots[(size_t)cb * 16 + lane];   // 4 cells' slots, coalesced
            #pragma unroll
            for (int i = 0; i < 2; ++i) {
                int j = i * 2 + hid;                  // this half's cell (of the 4)
                int c = cb + j;
                // wave-uniform counts for the pair of cells handled this pass
                int nA = cnt[cb + i * 2];     if (nA > 16) nA = 16;
                int nB = cnt[cb + i * 2 + 1]; if (nB > 16) nB = 16;
                int n    = hid ? nB : nA;             // own trip count
                int nmax = nA > nB ? nA : nB;         // wave-uniform bound
                float4 a0 = make_float4(0.f, 0.f, 0.f, 0.f);
                float4 a1 = a0;
                for (int s = 0; s < nmax; ++s) {
                    int f = __shfl(sl, j * 16 + s);   // ALL lanes active here
                    if (s < n) {
                        const float* src = FV + (size_t)f * 256 + hl * 4;
                        float4 v0 = *(const float4*)(src);         // cols hl*4
                        float4 v1 = *(const float4*)(src + 128);   // cols 128+hl*4
                        a0.x += v0.x; a0.y += v0.y; a0.z += v0.z; a0.w += v0.w;
                        a1.x += v1.x; a1.y += v1.y; a1.z += v1.z; a1.w += v1.w;
                    }
                }
                ushort4 o0, o1;
                o0.x = f2bf(a0.x); o0.y = f2bf(a0.y); o0.z = f2bf(a0.z); o0.w = f2bf(a0.w);
                o1.x = f2bf(a1.x); o1.y = f2bf(a1.y); o1.z = f2bf(a1.z); o1.w = f2bf(a1.w);
                unsigned short* dst = Abuf + (size_t)c * 256;
                *(ushort4*)(dst + hl * 4)       = o0;   // 256B contiguous/instr
                *(ushort4*)(dst + 128 + hl * 4) = o1;   // 256B contiguous/instr
            }
        }
        return;
    }

    // ---------------- mlp: 16 query rows x 256 N, LDS ping-pong ----------------
    const int m0 = blockIdx.x * 16;
    #pragma unroll
    for (int i = 0; i < 4; ++i) {
        int c = tid + i * 256;
        int row = c >> 6, kq = (c & 63) * 4;
        int gr = m0 + row; if (gr >= M) gr = M - 1;
        float4 v = *(const float4*)(Qf + (size_t)gr * 256 + kq);
        ushort4 o; o.x = f2bf(v.x); o.y = f2bf(v.y); o.z = f2bf(v.z); o.w = f2bf(v.w);
        *(ushort4*)&At[row * 264 + kq] = o;
    }
    __syncthreads();

    for (int l = 0; l < 4; ++l) {
        const unsigned short* Wl = Wb + (size_t)l * wsz;
        const float* bl = (l == 0) ? b0p : (l == 1) ? b1p : (l == 2) ? b2p : b3p;
        f32x4 acc[4] = {};
        #pragma unroll
        for (int k = 0; k < 256; k += 32) {
            bf16x8 af = *(const bf16x8*)&At[l16 * 264 + k + quad * 8];
            #pragma unroll
            for (int t = 0; t < 4; ++t) {
                int n = wid * 64 + t * 16 + l16;
                bf16x8 bfr = *(const bf16x8*)(Wl + (size_t)n * 256 + k + quad * 8);
                acc[t] = __builtin_amdgcn_mfma_f32_16x16x32_bf16(af, bfr, acc[t], 0, 0, 0);
            }
        }
        __syncthreads();
        #pragma unroll
        for (int t = 0; t < 4; ++t) {
            int n = wid * 64 + t * 16 + l16;
            float bv = bl[n];
            #pragma unroll
            for (int r = 0; r < 4; ++r) {
                int m = quad * 4 + r;
                float v = acc[t][r] + bv;
                if (l < 3) {
                    At[m * 264 + n] = f2bf(fmaxf(v, 0.f));
                } else {
                    if (m0 + m < M) outQB[(size_t)(m0 + m) * 256 + n] = f2bf(v);
                }
            }
        }
        if (l < 3) __syncthreads();
    }
}

// ---------------------------------------------------------------------------
// cell_gemm5: NO LDS. B-fragments are read directly from L1/L2-hot wsQB per
// MFMA (each k-step's B slice is ~19 KB -> fits L1; the 4 co-resident blocks
// of a CU share the same batch's QB). This deletes the staging loop, both
// per-k-step barriers, all ds_write/ds_read traffic and the 3.7M-cycle bank
// conflict that dominated cell_gemm3. A-fragments unchanged (global,
// prefetched one k-step ahead). No __syncthreads anywhere.
// ---------------------------------------------------------------------------
__global__ __launch_bounds__(256, 4) void cell_gemm5(
    const unsigned short* __restrict__ Abuf,
    const unsigned short* __restrict__ QB, const int* __restrict__ qoff,
    float* __restrict__ out, int cpb, int HW, int Qstride)
{
    const int tid = threadIdx.x;
    const int b   = blockIdx.x / cpb;
    const int c0  = (blockIdx.x - b * cpb) * 64;
    const size_t gc0 = (size_t)b * HW + c0;
    const int q0 = qoff[b];
    int qlen = qoff[b + 1] - q0; if (qlen < 1) qlen = 1;

    const int wid = tid >> 6, lane = tid & 63, quad = lane >> 4, l16 = lane & 15;

    // per-thread QB element offsets for the 19 q-tiles (row clamped to qlen-1
    // so the last batch never reads past the end of wsQB; garbage rows are
    // masked at the store)
    int qob[19];
    #pragma unroll
    for (int t = 0; t < 19; ++t) {
        int qr = t * 16 + l16; if (qr >= qlen) qr = qlen - 1;
        qob[t] = (q0 + qr) * 256;
    }

    // A-fragment pointer: row = c0 + wid*16 + l16, col base quad*8
    const unsigned short* aptr = Abuf + (gc0 + wid * 16 + l16) * 256 + quad * 8;
    bf16x8 afA = *(const bf16x8*)aptr;          // k0 = 0 fragment
    f32x4 acc[19] = {};

    for (int k0 = 0; k0 < 256; k0 += 32) {
        int k1 = (k0 + 32) & 255;               // wraps harmlessly on last iter
        bf16x8 afB = *(const bf16x8*)(aptr + k1);
        const unsigned short* qb = QB + k0 + quad * 8;
        #pragma unroll
        for (int t = 0; t < 19; ++t) {
            bf16x8 bfr = *(const bf16x8*)(qb + qob[t]);
            acc[t] = __builtin_amdgcn_mfma_f32_16x16x32_bf16(afA, bfr, acc[t], 0, 0, 0);
        }
        afA = afB;
    }

    // coalesced stores; zero-fill n >= qlen (no memset of d_out needed)
    #pragma unroll
    for (int r = 0; r < 4; ++r) {
        int m = quad * 4 + r;
        float* dst = out + (gc0 + wid * 16 + m) * Qstride;
        #pragma unroll
        for (int t = 0; t < 19; ++t) {
            int nq = t * 16 + l16;
            if (nq < Qstride) dst[nq] = (nq < qlen) ? acc[t][r] : 0.f;
        }
    }
}

extern "C" void kernel_launch(void* const* d_in, const int* in_sizes, int n_in,
                              void* d_out, int out_size, void* d_ws, size_t ws_size,
                              hipStream_t stream) {
    const float* queries = (const float*)d_in[0];
    const float* FV      = (const float*)d_in[1];
    const int*   FI      = (const int*)d_in[2];
    const int*   qoff    = (const int*)d_in[3];
    const int*   wptr    = (const int*)d_in[6];
    const float* W0 = (const float*)d_in[7];
    const float* b0 = (const float*)d_in[8];
    const float* W1 = (const float*)d_in[9];
    const float* b1 = (const float*)d_in[10];
    const float* W2 = (const float*)d_in[11];
    const float* b2 = (const float*)d_in[12];
    const float* W3 = (const float*)d_in[13];
    const float* b3 = (const float*)d_in[14];
    float* out = (float*)d_out;

    const int NQe = in_sizes[0];          // 307200
    const int NQ  = NQe / 256;            // 1200
    const int NF  = in_sizes[1] / 256;    // 65536
    const int WSZ = in_sizes[7];          // 65536
    const int B   = in_sizes[3] - 1;      // 4
    const int Q   = NQ / B;               // 300
    const int HW  = out_size / (B * Q);   // 16384
    const int NC  = B * HW;               // 65536 cells
    const int cpb = HW / 64;              // 256 blocks per batch

    int* cnt   = (int*)d_ws;                                   // NC ints
    int* slots = cnt + (size_t)NC;                             // NC*16 ints
    unsigned short* wsW  = (unsigned short*)(slots + (size_t)NC * 16);  // 4*WSZ
    unsigned short* wsQB = wsW + (size_t)4 * WSZ;              // NQe bf16
    unsigned short* Abuf = wsQB + (size_t)NQe;                 // NC*256 bf16

    hipMemsetAsync(cnt, 0, (size_t)NC * sizeof(int), stream);

    const int nbBin = (NF + 255) / 256;
    const int nbW   = (4 * WSZ / 4 + 255) / 256;
    prep<<<nbBin + nbW, 256, 0, stream>>>(FI, wptr, cnt, slots,
                                          W0, W1, W2, W3, wsW, NF, HW, WSZ, nbBin);

    const int nbM = (NQ + 15) / 16;       // 75 mlp blocks
    const int nbG = 4096;                 // gather blocks (half-wave per cell)
    gather_mlp<<<nbM + nbG, 256, 0, stream>>>(
        queries, wsW, b0, b1, b2, b3, wsQB, NQ, WSZ,
        FV, cnt, slots, Abuf, NC, nbM, nbG);

    cell_gemm5<<<B * cpb, 256, 0, stream>>>(Abuf, wsQB, qoff, out, cpb, HW, Q);
}

// Round 7
// 233.409 us; speedup vs baseline: 1.3288x; 1.3288x over previous
//
#include <hip/hip_runtime.h>
#include <hip/hip_bf16.h>
#include <stdint.h>

typedef __attribute__((ext_vector_type(8))) short bf16x8;
typedef __attribute__((ext_vector_type(4))) float f32x4;

__device__ __forceinline__ unsigned short f2bf(float f) {
    union { float f; unsigned u; } v; v.f = f;
    unsigned u = v.u;
    u += 0x7fff + ((u >> 16) & 1);   // round-to-nearest-even
    return (unsigned short)(u >> 16);
}

// ---------------------------------------------------------------------------
// prep: blocks [0, nbBin): binner (slot claim per feature).
//       blocks [nbBin, nbBin+nbW): convert W0..W3 fp32 -> bf16 into wsW.
// ---------------------------------------------------------------------------
__global__ __launch_bounds__(256) void prep(
    const int* __restrict__ FI, const int* __restrict__ wptr,
    int* __restrict__ cnt, int* __restrict__ slots,
    const float* __restrict__ W0, const float* __restrict__ W1,
    const float* __restrict__ W2, const float* __restrict__ W3,
    unsigned short* __restrict__ wsW,
    int NF, int HW, int wsz, int nbBin)
{
    int blk = blockIdx.x;
    if (blk < nbBin) {
        int i = blk * 256 + threadIdx.x;
        if (i >= NF) return;
        int Wd = *wptr;
        int b = FI[(size_t)i * 3];
        int h = FI[(size_t)i * 3 + 1];
        int w = FI[(size_t)i * 3 + 2];
        int gc = b * HW + h * Wd + w;
        int slot = atomicAdd(&cnt[gc], 1);
        if (slot < 16) slots[(size_t)gc * 16 + slot] = i;
    } else {
        int idx = ((blk - nbBin) * 256 + threadIdx.x) * 4;
        if (idx >= 4 * wsz) return;
        int l = idx / wsz, off = idx - l * wsz;
        const float* Ws = (l == 0) ? W0 : (l == 1) ? W1 : (l == 2) ? W2 : W3;
        float4 v = *(const float4*)(Ws + off);
        ushort4 o; o.x = f2bf(v.x); o.y = f2bf(v.y); o.z = f2bf(v.z); o.w = f2bf(v.w);
        *(ushort4*)(wsW + (size_t)l * wsz + off) = o;
    }
}

// ---------------------------------------------------------------------------
// gather_mlp: blocks [0, nbM): fused 4-layer MLP.
//             blocks [nbM, nbM+nbG): cell gather, HALF-WAVE per cell.
// (round-4 verified version — best measured config, 198.9 us total)
//   - lane hl owns cols {hl*4..+3} and {128+hl*4..+3} of its cell
//   - FV loads: float4, 16B lane stride -> 512B contiguous per instruction
//   - Abuf stores: ushort4, 8B lane stride -> 256B full-line per instruction
//   - loop bound nmax is WAVE-UNIFORM so every __shfl has all 64 lanes active
// ---------------------------------------------------------------------------
__global__ __launch_bounds__(256) void gather_mlp(
    // mlp args
    const float* __restrict__ Qf, const unsigned short* __restrict__ Wb,
    const float* __restrict__ b0p, const float* __restrict__ b1p,
    const float* __restrict__ b2p, const float* __restrict__ b3p,
    unsigned short* __restrict__ outQB, int M, int wsz,
    // gather args
    const float* __restrict__ FV, const int* __restrict__ cnt,
    const int* __restrict__ slots, unsigned short* __restrict__ Abuf, int NC,
    int nbM, int nbG)
{
    __shared__ unsigned short At[16 * 264];
    const int tid = threadIdx.x;
    const int wid = tid >> 6, lane = tid & 63, quad = lane >> 4, l16 = lane & 15;

    if (blockIdx.x >= nbM) {
        // ------------- gather: half-wave per cell, 4 cells per wave -------------
        const int hl  = lane & 31;      // half-lane
        const int hid = lane >> 5;      // which half of the wave
        const int wg = (blockIdx.x - nbM) * 4 + wid;
        const int nw = nbG * 4;
        for (int cb = wg * 4; cb < NC; cb += nw * 4) {
            int sl = slots[(size_t)cb * 16 + lane];   // 4 cells' slots, coalesced
            #pragma unroll
            for (int i = 0; i < 2; ++i) {
                int j = i * 2 + hid;                  // this half's cell (of the 4)
                int c = cb + j;
                // wave-uniform counts for the pair of cells handled this pass
                int nA = cnt[cb + i * 2];     if (nA > 16) nA = 16;
                int nB = cnt[cb + i * 2 + 1]; if (nB > 16) nB = 16;
                int n    = hid ? nB : nA;             // own trip count
                int nmax = nA > nB ? nA : nB;         // wave-uniform bound
                float4 a0 = make_float4(0.f, 0.f, 0.f, 0.f);
                float4 a1 = a0;
                for (int s = 0; s < nmax; ++s) {
                    int f = __shfl(sl, j * 16 + s);   // ALL lanes active here
                    if (s < n) {
                        const float* src = FV + (size_t)f * 256 + hl * 4;
                        float4 v0 = *(const float4*)(src);         // cols hl*4
                        float4 v1 = *(const float4*)(src + 128);   // cols 128+hl*4
                        a0.x += v0.x; a0.y += v0.y; a0.z += v0.z; a0.w += v0.w;
                        a1.x += v1.x; a1.y += v1.y; a1.z += v1.z; a1.w += v1.w;
                    }
                }
                ushort4 o0, o1;
                o0.x = f2bf(a0.x); o0.y = f2bf(a0.y); o0.z = f2bf(a0.z); o0.w = f2bf(a0.w);
                o1.x = f2bf(a1.x); o1.y = f2bf(a1.y); o1.z = f2bf(a1.z); o1.w = f2bf(a1.w);
                unsigned short* dst = Abuf + (size_t)c * 256;
                *(ushort4*)(dst + hl * 4)       = o0;   // 256B contiguous/instr
                *(ushort4*)(dst + 128 + hl * 4) = o1;   // 256B contiguous/instr
            }
        }
        return;
    }

    // ---------------- mlp: 16 query rows x 256 N, LDS ping-pong ----------------
    const int m0 = blockIdx.x * 16;
    #pragma unroll
    for (int i = 0; i < 4; ++i) {
        int c = tid + i * 256;
        int row = c >> 6, kq = (c & 63) * 4;
        int gr = m0 + row; if (gr >= M) gr = M - 1;
        float4 v = *(const float4*)(Qf + (size_t)gr * 256 + kq);
        ushort4 o; o.x = f2bf(v.x); o.y = f2bf(v.y); o.z = f2bf(v.z); o.w = f2bf(v.w);
        *(ushort4*)&At[row * 264 + kq] = o;
    }
    __syncthreads();

    for (int l = 0; l < 4; ++l) {
        const unsigned short* Wl = Wb + (size_t)l * wsz;
        const float* bl = (l == 0) ? b0p : (l == 1) ? b1p : (l == 2) ? b2p : b3p;
        f32x4 acc[4] = {};
        #pragma unroll
        for (int k = 0; k < 256; k += 32) {
            bf16x8 af = *(const bf16x8*)&At[l16 * 264 + k + quad * 8];
            #pragma unroll
            for (int t = 0; t < 4; ++t) {
                int n = wid * 64 + t * 16 + l16;
                bf16x8 bfr = *(const bf16x8*)(Wl + (size_t)n * 256 + k + quad * 8);
                acc[t] = __builtin_amdgcn_mfma_f32_16x16x32_bf16(af, bfr, acc[t], 0, 0, 0);
            }
        }
        __syncthreads();
        #pragma unroll
        for (int t = 0; t < 4; ++t) {
            int n = wid * 64 + t * 16 + l16;
            float bv = bl[n];
            #pragma unroll
            for (int r = 0; r < 4; ++r) {
                int m = quad * 4 + r;
                float v = acc[t][r] + bv;
                if (l < 3) {
                    At[m * 264 + n] = f2bf(fmaxf(v, 0.f));
                } else {
                    if (m0 + m < M) outQB[(size_t)(m0 + m) * 256 + n] = f2bf(v);
                }
            }
        }
        if (l < 3) __syncthreads();
    }
}

// ---------------------------------------------------------------------------
// cell_gemm6: LDS-staged gemm (gemm3 structure — empirically load-bearing,
// see round-6 post-mortem) with two targeted fixes:
//  (1) Bsm stride 40 -> 36 ushorts (72B). Old 80B stride aliased lanes l16 and
//      l16+8 of each quad onto one bank (3.7M conflict cycles). 18*l16 mod 32
//      is distinct for all 16 lanes -> conflict-free ds_read_b128; ds_write
//      drops to 2-way (free). LDS 21.9 KB -> still 4 blocks/CU.
//  (2) T14 async-stage split: issue next k-slice's global loads into registers
//      BEFORE the MFMA phase, ds_write them AFTER the post-read barrier. The
//      ~300-900cy L2/L3 load latency hides under 19 MFMA + 19 ds_read instead
//      of sitting serially between barriers.
// ---------------------------------------------------------------------------
__global__ __launch_bounds__(256, 4) void cell_gemm6(
    const unsigned short* __restrict__ Abuf,
    const unsigned short* __restrict__ QB, const int* __restrict__ qoff,
    float* __restrict__ out, int cpb, int HW, int Qstride)
{
    __shared__ unsigned short Bsm[304 * 36];   // 21888 B

    const int tid = threadIdx.x;
    const int b   = blockIdx.x / cpb;
    const int c0  = (blockIdx.x - b * cpb) * 64;
    const size_t gc0 = (size_t)b * HW + c0;
    const int q0 = qoff[b];
    int qlen = qoff[b + 1] - q0; if (qlen < 1) qlen = 1;

    const int wid = tid >> 6, lane = tid & 63, quad = lane >> 4, l16 = lane & 15;

    // per-thread staging coords (5 chunks of 256 threads cover 1216 uint4)
    int srow[5], skc[5];
    #pragma unroll
    for (int i = 0; i < 5; ++i) {
        int c = tid + i * 256;
        int row = c >> 2;
        srow[i] = row;
        skc[i]  = (c & 3) * 8;
    }
    const unsigned short* qbase[5];
    #pragma unroll
    for (int i = 0; i < 5; ++i) {
        int qr = srow[i] < qlen ? srow[i] : qlen - 1;
        qbase[i] = QB + (size_t)(q0 + qr) * 256 + skc[i];
    }

    // A-fragment pointer: row = c0 + wid*16 + l16, col base quad*8
    const unsigned short* aptr = Abuf + (gc0 + wid * 16 + l16) * 256 + quad * 8;
    bf16x8 afA = *(const bf16x8*)aptr;          // k0 = 0 fragment
    f32x4 acc[19] = {};

    // prologue: stage k-slice 0
    uint4 st[5];
    #pragma unroll
    for (int i = 0; i < 5; ++i)
        if (srow[i] < 304) st[i] = *(const uint4*)(qbase[i]);
    #pragma unroll
    for (int i = 0; i < 5; ++i)
        if (srow[i] < 304) *(uint4*)&Bsm[srow[i] * 36 + skc[i]] = st[i];
    __syncthreads();

    for (int k0 = 0; k0 < 256; k0 += 32) {
        const bool nxt = (k0 + 32 < 256);
        // issue next slice's global loads early (latency hides under MFMA)
        if (nxt) {
            #pragma unroll
            for (int i = 0; i < 5; ++i)
                if (srow[i] < 304) st[i] = *(const uint4*)(qbase[i] + k0 + 32);
        }
        bf16x8 afB = afA;
        if (nxt) afB = *(const bf16x8*)(aptr + k0 + 32);
        #pragma unroll
        for (int t = 0; t < 19; ++t) {
            bf16x8 bfr = *(const bf16x8*)&Bsm[(t * 16 + l16) * 36 + quad * 8];
            acc[t] = __builtin_amdgcn_mfma_f32_16x16x32_bf16(afA, bfr, acc[t], 0, 0, 0);
        }
        if (nxt) {
            __syncthreads();               // all waves done reading Bsm
            #pragma unroll
            for (int i = 0; i < 5; ++i)
                if (srow[i] < 304) *(uint4*)&Bsm[srow[i] * 36 + skc[i]] = st[i];
            __syncthreads();               // next slice ready
        }
        afA = afB;
    }

    // coalesced stores; zero-fill n >= qlen (no memset of d_out needed)
    #pragma unroll
    for (int r = 0; r < 4; ++r) {
        int m = quad * 4 + r;
        float* dst = out + (gc0 + wid * 16 + m) * Qstride;
        #pragma unroll
        for (int t = 0; t < 19; ++t) {
            int nq = t * 16 + l16;
            if (nq < Qstride) dst[nq] = (nq < qlen) ? acc[t][r] : 0.f;
        }
    }
}

extern "C" void kernel_launch(void* const* d_in, const int* in_sizes, int n_in,
                              void* d_out, int out_size, void* d_ws, size_t ws_size,
                              hipStream_t stream) {
    const float* queries = (const float*)d_in[0];
    const float* FV      = (const float*)d_in[1];
    const int*   FI      = (const int*)d_in[2];
    const int*   qoff    = (const int*)d_in[3];
    const int*   wptr    = (const int*)d_in[6];
    const float* W0 = (const float*)d_in[7];
    const float* b0 = (const float*)d_in[8];
    const float* W1 = (const float*)d_in[9];
    const float* b1 = (const float*)d_in[10];
    const float* W2 = (const float*)d_in[11];
    const float* b2 = (const float*)d_in[12];
    const float* W3 = (const float*)d_in[13];
    const float* b3 = (const float*)d_in[14];
    float* out = (float*)d_out;

    const int NQe = in_sizes[0];          // 307200
    const int NQ  = NQe / 256;            // 1200
    const int NF  = in_sizes[1] / 256;    // 65536
    const int WSZ = in_sizes[7];          // 65536
    const int B   = in_sizes[3] - 1;      // 4
    const int Q   = NQ / B;               // 300
    const int HW  = out_size / (B * Q);   // 16384
    const int NC  = B * HW;               // 65536 cells
    const int cpb = HW / 64;              // 256 blocks per batch

    int* cnt   = (int*)d_ws;                                   // NC ints
    int* slots = cnt + (size_t)NC;                             // NC*16 ints
    unsigned short* wsW  = (unsigned short*)(slots + (size_t)NC * 16);  // 4*WSZ
    unsigned short* wsQB = wsW + (size_t)4 * WSZ;              // NQe bf16
    unsigned short* Abuf = wsQB + (size_t)NQe;                 // NC*256 bf16

    hipMemsetAsync(cnt, 0, (size_t)NC * sizeof(int), stream);

    const int nbBin = (NF + 255) / 256;
    const int nbW   = (4 * WSZ / 4 + 255) / 256;
    prep<<<nbBin + nbW, 256, 0, stream>>>(FI, wptr, cnt, slots,
                                          W0, W1, W2, W3, wsW, NF, HW, WSZ, nbBin);

    const int nbM = (NQ + 15) / 16;       // 75 mlp blocks
    const int nbG = 4096;                 // gather blocks (half-wave per cell)
    gather_mlp<<<nbM + nbG, 256, 0, stream>>>(
        queries, wsW, b0, b1, b2, b3, wsQB, NQ, WSZ,
        FV, cnt, slots, Abuf, NC, nbM, nbG);

    cell_gemm6<<<B * cpb, 256, 0, stream>>>(Abuf, wsQB, qoff, out, cpb, HW, Q);
}

// Round 8
// 200.505 us; speedup vs baseline: 1.5468x; 1.1641x over previous
//
#include <hip/hip_runtime.h>
#include <hip/hip_bf16.h>
#include <stdint.h>

typedef __attribute__((ext_vector_type(8))) short bf16x8;
typedef __attribute__((ext_vector_type(4))) float f32x4;

__device__ __forceinline__ unsigned short f2bf(float f) {
    union { float f; unsigned u; } v; v.f = f;
    unsigned u = v.u;
    u += 0x7fff + ((u >> 16) & 1);   // round-to-nearest-even
    return (unsigned short)(u >> 16);
}

// ---------------------------------------------------------------------------
// prep: blocks [0, nbBin): binner (slot claim per feature).
//       blocks [nbBin, nbBin+nbW): convert W0..W3 fp32 -> bf16 into wsW.
// ---------------------------------------------------------------------------
__global__ __launch_bounds__(256) void prep(
    const int* __restrict__ FI, const int* __restrict__ wptr,
    int* __restrict__ cnt, int* __restrict__ slots,
    const float* __restrict__ W0, const float* __restrict__ W1,
    const float* __restrict__ W2, const float* __restrict__ W3,
    unsigned short* __restrict__ wsW,
    int NF, int HW, int wsz, int nbBin)
{
    int blk = blockIdx.x;
    if (blk < nbBin) {
        int i = blk * 256 + threadIdx.x;
        if (i >= NF) return;
        int Wd = *wptr;
        int b = FI[(size_t)i * 3];
        int h = FI[(size_t)i * 3 + 1];
        int w = FI[(size_t)i * 3 + 2];
        int gc = b * HW + h * Wd + w;
        int slot = atomicAdd(&cnt[gc], 1);
        if (slot < 16) slots[(size_t)gc * 16 + slot] = i;
    } else {
        int idx = ((blk - nbBin) * 256 + threadIdx.x) * 4;
        if (idx >= 4 * wsz) return;
        int l = idx / wsz, off = idx - l * wsz;
        const float* Ws = (l == 0) ? W0 : (l == 1) ? W1 : (l == 2) ? W2 : W3;
        float4 v = *(const float4*)(Ws + off);
        ushort4 o; o.x = f2bf(v.x); o.y = f2bf(v.y); o.z = f2bf(v.z); o.w = f2bf(v.w);
        *(ushort4*)(wsW + (size_t)l * wsz + off) = o;
    }
}

// ---------------------------------------------------------------------------
// gather_mlp: blocks [0, nbM): fused 4-layer MLP.
//             blocks [nbM, nbM+nbG): cell gather, HALF-WAVE per cell.
// (round-4 verified version — best measured config, 198.9 us total)
// ---------------------------------------------------------------------------
__global__ __launch_bounds__(256) void gather_mlp(
    // mlp args
    const float* __restrict__ Qf, const unsigned short* __restrict__ Wb,
    const float* __restrict__ b0p, const float* __restrict__ b1p,
    const float* __restrict__ b2p, const float* __restrict__ b3p,
    unsigned short* __restrict__ outQB, int M, int wsz,
    // gather args
    const float* __restrict__ FV, const int* __restrict__ cnt,
    const int* __restrict__ slots, unsigned short* __restrict__ Abuf, int NC,
    int nbM, int nbG)
{
    __shared__ unsigned short At[16 * 264];
    const int tid = threadIdx.x;
    const int wid = tid >> 6, lane = tid & 63, quad = lane >> 4, l16 = lane & 15;

    if (blockIdx.x >= nbM) {
        // ------------- gather: half-wave per cell, 4 cells per wave -------------
        const int hl  = lane & 31;      // half-lane
        const int hid = lane >> 5;      // which half of the wave
        const int wg = (blockIdx.x - nbM) * 4 + wid;
        const int nw = nbG * 4;
        for (int cb = wg * 4; cb < NC; cb += nw * 4) {
            int sl = slots[(size_t)cb * 16 + lane];   // 4 cells' slots, coalesced
            #pragma unroll
            for (int i = 0; i < 2; ++i) {
                int j = i * 2 + hid;                  // this half's cell (of the 4)
                int c = cb + j;
                // wave-uniform counts for the pair of cells handled this pass
                int nA = cnt[cb + i * 2];     if (nA > 16) nA = 16;
                int nB = cnt[cb + i * 2 + 1]; if (nB > 16) nB = 16;
                int n    = hid ? nB : nA;             // own trip count
                int nmax = nA > nB ? nA : nB;         // wave-uniform bound
                float4 a0 = make_float4(0.f, 0.f, 0.f, 0.f);
                float4 a1 = a0;
                for (int s = 0; s < nmax; ++s) {
                    int f = __shfl(sl, j * 16 + s);   // ALL lanes active here
                    if (s < n) {
                        const float* src = FV + (size_t)f * 256 + hl * 4;
                        float4 v0 = *(const float4*)(src);         // cols hl*4
                        float4 v1 = *(const float4*)(src + 128);   // cols 128+hl*4
                        a0.x += v0.x; a0.y += v0.y; a0.z += v0.z; a0.w += v0.w;
                        a1.x += v1.x; a1.y += v1.y; a1.z += v1.z; a1.w += v1.w;
                    }
                }
                ushort4 o0, o1;
                o0.x = f2bf(a0.x); o0.y = f2bf(a0.y); o0.z = f2bf(a0.z); o0.w = f2bf(a0.w);
                o1.x = f2bf(a1.x); o1.y = f2bf(a1.y); o1.z = f2bf(a1.z); o1.w = f2bf(a1.w);
                unsigned short* dst = Abuf + (size_t)c * 256;
                *(ushort4*)(dst + hl * 4)       = o0;   // 256B contiguous/instr
                *(ushort4*)(dst + 128 + hl * 4) = o1;   // 256B contiguous/instr
            }
        }
        return;
    }

    // ---------------- mlp: 16 query rows x 256 N, LDS ping-pong ----------------
    const int m0 = blockIdx.x * 16;
    #pragma unroll
    for (int i = 0; i < 4; ++i) {
        int c = tid + i * 256;
        int row = c >> 6, kq = (c & 63) * 4;
        int gr = m0 + row; if (gr >= M) gr = M - 1;
        float4 v = *(const float4*)(Qf + (size_t)gr * 256 + kq);
        ushort4 o; o.x = f2bf(v.x); o.y = f2bf(v.y); o.z = f2bf(v.z); o.w = f2bf(v.w);
        *(ushort4*)&At[row * 264 + kq] = o;
    }
    __syncthreads();

    for (int l = 0; l < 4; ++l) {
        const unsigned short* Wl = Wb + (size_t)l * wsz;
        const float* bl = (l == 0) ? b0p : (l == 1) ? b1p : (l == 2) ? b2p : b3p;
        f32x4 acc[4] = {};
        #pragma unroll
        for (int k = 0; k < 256; k += 32) {
            bf16x8 af = *(const bf16x8*)&At[l16 * 264 + k + quad * 8];
            #pragma unroll
            for (int t = 0; t < 4; ++t) {
                int n = wid * 64 + t * 16 + l16;
                bf16x8 bfr = *(const bf16x8*)(Wl + (size_t)n * 256 + k + quad * 8);
                acc[t] = __builtin_amdgcn_mfma_f32_16x16x32_bf16(af, bfr, acc[t], 0, 0, 0);
            }
        }
        __syncthreads();
        #pragma unroll
        for (int t = 0; t < 4; ++t) {
            int n = wid * 64 + t * 16 + l16;
            float bv = bl[n];
            #pragma unroll
            for (int r = 0; r < 4; ++r) {
                int m = quad * 4 + r;
                float v = acc[t][r] + bv;
                if (l < 3) {
                    At[m * 264 + n] = f2bf(fmaxf(v, 0.f));
                } else {
                    if (m0 + m < M) outQB[(size_t)(m0 + m) * 256 + n] = f2bf(v);
                }
            }
        }
        if (l < 3) __syncthreads();
    }
}

// ---------------------------------------------------------------------------
// cell_gemm7: gemm3 structure with 32 CELLS PER WAVE (2 m-tiles). Each staged
// Bsm slice now feeds 38 MFMAs/wave instead of 19, so per-CU LDS read traffic
// (the measured ~21us bottleneck: 16 waves x 8 iters x 19 ds_read_b128, all
// 4 waves reading identical bytes) halves. Block = 128 cells, grid = 512,
// 2 blocks/CU. Registers: 152 AGPR acc + ~70 VGPR < 256/wave budget -> no
// spills (round-7 failure mode). Synchronous staging (no T14). Stride 40
// kept: reads are pure 2-way (free per m136); conflicts are write-side only.
// ---------------------------------------------------------------------------
__global__ __launch_bounds__(256, 2) void cell_gemm7(
    const unsigned short* __restrict__ Abuf,
    const unsigned short* __restrict__ QB, const int* __restrict__ qoff,
    float* __restrict__ out, int cpb, int HW, int Qstride)
{
    __shared__ unsigned short Bsm[304 * 40];   // 24320 B

    const int tid = threadIdx.x;
    const int b   = blockIdx.x / cpb;
    const int c0  = (blockIdx.x - b * cpb) * 128;
    const size_t gc0 = (size_t)b * HW + c0;
    const int q0 = qoff[b];
    int qlen = qoff[b + 1] - q0; if (qlen < 1) qlen = 1;

    const int wid = tid >> 6, lane = tid & 63, quad = lane >> 4, l16 = lane & 15;

    // A-fragment pointers: m-tile0 rows c0+wid*16+l16, m-tile1 rows +64
    const unsigned short* aptr0 = Abuf + (gc0 + wid * 16 + l16) * 256 + quad * 8;
    const unsigned short* aptr1 = aptr0 + 64 * 256;
    bf16x8 afA0 = *(const bf16x8*)aptr0;
    bf16x8 afA1 = *(const bf16x8*)aptr1;
    f32x4 acc0[19] = {};
    f32x4 acc1[19] = {};

    for (int k0 = 0; k0 < 256; k0 += 32) {
        // stage B: 304 q-rows x 32 k bf16, padded stride 40
        for (int c = tid; c < 1216; c += 256) {
            int row = c >> 2, kc = (c & 3) * 8;
            int qr = row < qlen ? row : qlen - 1;
            uint4 v = *(const uint4*)(QB + (size_t)(q0 + qr) * 256 + k0 + kc);
            *(uint4*)&Bsm[row * 40 + kc] = v;
        }
        int k1 = (k0 + 32) & 255;               // wraps harmlessly on last iter
        bf16x8 afB0 = *(const bf16x8*)(aptr0 + k1);
        bf16x8 afB1 = *(const bf16x8*)(aptr1 + k1);
        __syncthreads();
        #pragma unroll
        for (int t = 0; t < 19; ++t) {
            bf16x8 bfr = *(const bf16x8*)&Bsm[(t * 16 + l16) * 40 + quad * 8];
            acc0[t] = __builtin_amdgcn_mfma_f32_16x16x32_bf16(afA0, bfr, acc0[t], 0, 0, 0);
            acc1[t] = __builtin_amdgcn_mfma_f32_16x16x32_bf16(afA1, bfr, acc1[t], 0, 0, 0);
        }
        __syncthreads();
        afA0 = afB0; afA1 = afB1;
    }

    // coalesced stores; zero-fill n >= qlen (no memset of d_out needed)
    #pragma unroll
    for (int r = 0; r < 4; ++r) {
        int m = quad * 4 + r;
        float* dst0 = out + (gc0 + wid * 16 + m) * Qstride;
        float* dst1 = out + (gc0 + 64 + wid * 16 + m) * Qstride;
        #pragma unroll
        for (int t = 0; t < 19; ++t) {
            int nq = t * 16 + l16;
            if (nq < Qstride) {
                dst0[nq] = (nq < qlen) ? acc0[t][r] : 0.f;
                dst1[nq] = (nq < qlen) ? acc1[t][r] : 0.f;
            }
        }
    }
}

extern "C" void kernel_launch(void* const* d_in, const int* in_sizes, int n_in,
                              void* d_out, int out_size, void* d_ws, size_t ws_size,
                              hipStream_t stream) {
    const float* queries = (const float*)d_in[0];
    const float* FV      = (const float*)d_in[1];
    const int*   FI      = (const int*)d_in[2];
    const int*   qoff    = (const int*)d_in[3];
    const int*   wptr    = (const int*)d_in[6];
    const float* W0 = (const float*)d_in[7];
    const float* b0 = (const float*)d_in[8];
    const float* W1 = (const float*)d_in[9];
    const float* b1 = (const float*)d_in[10];
    const float* W2 = (const float*)d_in[11];
    const float* b2 = (const float*)d_in[12];
    const float* W3 = (const float*)d_in[13];
    const float* b3 = (const float*)d_in[14];
    float* out = (float*)d_out;

    const int NQe = in_sizes[0];          // 307200
    const int NQ  = NQe / 256;            // 1200
    const int NF  = in_sizes[1] / 256;    // 65536
    const int WSZ = in_sizes[7];          // 65536
    const int B   = in_sizes[3] - 1;      // 4
    const int Q   = NQ / B;               // 300
    const int HW  = out_size / (B * Q);   // 16384
    const int NC  = B * HW;               // 65536 cells
    const int cpb = HW / 128;             // 128 blocks per batch (128-cell tiles)

    int* cnt   = (int*)d_ws;                                   // NC ints
    int* slots = cnt + (size_t)NC;                             // NC*16 ints
    unsigned short* wsW  = (unsigned short*)(slots + (size_t)NC * 16);  // 4*WSZ
    unsigned short* wsQB = wsW + (size_t)4 * WSZ;              // NQe bf16
    unsigned short* Abuf = wsQB + (size_t)NQe;                 // NC*256 bf16

    hipMemsetAsync(cnt, 0, (size_t)NC * sizeof(int), stream);

    const int nbBin = (NF + 255) / 256;
    const int nbW   = (4 * WSZ / 4 + 255) / 256;
    prep<<<nbBin + nbW, 256, 0, stream>>>(FI, wptr, cnt, slots,
                                          W0, W1, W2, W3, wsW, NF, HW, WSZ, nbBin);

    const int nbM = (NQ + 15) / 16;       // 75 mlp blocks
    const int nbG = 4096;                 // gather blocks (half-wave per cell)
    gather_mlp<<<nbM + nbG, 256, 0, stream>>>(
        queries, wsW, b0, b1, b2, b3, wsQB, NQ, WSZ,
        FV, cnt, slots, Abuf, NC, nbM, nbG);

    cell_gemm7<<<B * cpb, 256, 0, stream>>>(Abuf, wsQB, qoff, out, cpb, HW, Q);
}

// Round 9
// 192.098 us; speedup vs baseline: 1.6145x; 1.0438x over previous
//
#include <hip/hip_runtime.h>
#include <hip/hip_bf16.h>
#include <stdint.h>

typedef __attribute__((ext_vector_type(8))) short bf16x8;
typedef __attribute__((ext_vector_type(4))) float f32x4;

__device__ __forceinline__ unsigned short f2bf(float f) {
    union { float f; unsigned u; } v; v.f = f;
    unsigned u = v.u;
    u += 0x7fff + ((u >> 16) & 1);   // round-to-nearest-even
    return (unsigned short)(u >> 16);
}

// ---------------------------------------------------------------------------
// prep: blocks [0, nbBin): binner (slot claim per feature).
//       blocks [nbBin, nbBin+nbW): convert W0..W3 fp32 -> bf16 into wsW.
// ---------------------------------------------------------------------------
__global__ __launch_bounds__(256) void prep(
    const int* __restrict__ FI, const int* __restrict__ wptr,
    int* __restrict__ cnt, int* __restrict__ slots,
    const float* __restrict__ W0, const float* __restrict__ W1,
    const float* __restrict__ W2, const float* __restrict__ W3,
    unsigned short* __restrict__ wsW,
    int NF, int HW, int wsz, int nbBin)
{
    int blk = blockIdx.x;
    if (blk < nbBin) {
        int i = blk * 256 + threadIdx.x;
        if (i >= NF) return;
        int Wd = *wptr;
        int b = FI[(size_t)i * 3];
        int h = FI[(size_t)i * 3 + 1];
        int w = FI[(size_t)i * 3 + 2];
        int gc = b * HW + h * Wd + w;
        int slot = atomicAdd(&cnt[gc], 1);
        if (slot < 16) slots[(size_t)gc * 16 + slot] = i;
    } else {
        int idx = ((blk - nbBin) * 256 + threadIdx.x) * 4;
        if (idx >= 4 * wsz) return;
        int l = idx / wsz, off = idx - l * wsz;
        const float* Ws = (l == 0) ? W0 : (l == 1) ? W1 : (l == 2) ? W2 : W3;
        float4 v = *(const float4*)(Ws + off);
        ushort4 o; o.x = f2bf(v.x); o.y = f2bf(v.y); o.z = f2bf(v.z); o.w = f2bf(v.w);
        *(ushort4*)(wsW + (size_t)l * wsz + off) = o;
    }
}

// ---------------------------------------------------------------------------
// gather_mlp: blocks [0, nbM): fused 4-layer MLP.
//             blocks [nbM, nbM+nbG): cell gather, HALF-WAVE per cell.
// (round-4 verified version — best measured config)
// ---------------------------------------------------------------------------
__global__ __launch_bounds__(256) void gather_mlp(
    // mlp args
    const float* __restrict__ Qf, const unsigned short* __restrict__ Wb,
    const float* __restrict__ b0p, const float* __restrict__ b1p,
    const float* __restrict__ b2p, const float* __restrict__ b3p,
    unsigned short* __restrict__ outQB, int M, int wsz,
    // gather args
    const float* __restrict__ FV, const int* __restrict__ cnt,
    const int* __restrict__ slots, unsigned short* __restrict__ Abuf, int NC,
    int nbM, int nbG)
{
    __shared__ unsigned short At[16 * 264];
    const int tid = threadIdx.x;
    const int wid = tid >> 6, lane = tid & 63, quad = lane >> 4, l16 = lane & 15;

    if (blockIdx.x >= nbM) {
        // ------------- gather: half-wave per cell, 4 cells per wave -------------
        const int hl  = lane & 31;      // half-lane
        const int hid = lane >> 5;      // which half of the wave
        const int wg = (blockIdx.x - nbM) * 4 + wid;
        const int nw = nbG * 4;
        for (int cb = wg * 4; cb < NC; cb += nw * 4) {
            int sl = slots[(size_t)cb * 16 + lane];   // 4 cells' slots, coalesced
            #pragma unroll
            for (int i = 0; i < 2; ++i) {
                int j = i * 2 + hid;                  // this half's cell (of the 4)
                int c = cb + j;
                // wave-uniform counts for the pair of cells handled this pass
                int nA = cnt[cb + i * 2];     if (nA > 16) nA = 16;
                int nB = cnt[cb + i * 2 + 1]; if (nB > 16) nB = 16;
                int n    = hid ? nB : nA;             // own trip count
                int nmax = nA > nB ? nA : nB;         // wave-uniform bound
                float4 a0 = make_float4(0.f, 0.f, 0.f, 0.f);
                float4 a1 = a0;
                for (int s = 0; s < nmax; ++s) {
                    int f = __shfl(sl, j * 16 + s);   // ALL lanes active here
                    if (s < n) {
                        const float* src = FV + (size_t)f * 256 + hl * 4;
                        float4 v0 = *(const float4*)(src);         // cols hl*4
                        float4 v1 = *(const float4*)(src + 128);   // cols 128+hl*4
                        a0.x += v0.x; a0.y += v0.y; a0.z += v0.z; a0.w += v0.w;
                        a1.x += v1.x; a1.y += v1.y; a1.z += v1.z; a1.w += v1.w;
                    }
                }
                ushort4 o0, o1;
                o0.x = f2bf(a0.x); o0.y = f2bf(a0.y); o0.z = f2bf(a0.z); o0.w = f2bf(a0.w);
                o1.x = f2bf(a1.x); o1.y = f2bf(a1.y); o1.z = f2bf(a1.z); o1.w = f2bf(a1.w);
                unsigned short* dst = Abuf + (size_t)c * 256;
                *(ushort4*)(dst + hl * 4)       = o0;   // 256B contiguous/instr
                *(ushort4*)(dst + 128 + hl * 4) = o1;   // 256B contiguous/instr
            }
        }
        return;
    }

    // ---------------- mlp: 16 query rows x 256 N, LDS ping-pong ----------------
    const int m0 = blockIdx.x * 16;
    #pragma unroll
    for (int i = 0; i < 4; ++i) {
        int c = tid + i * 256;
        int row = c >> 6, kq = (c & 63) * 4;
        int gr = m0 + row; if (gr >= M) gr = M - 1;
        float4 v = *(const float4*)(Qf + (size_t)gr * 256 + kq);
        ushort4 o; o.x = f2bf(v.x); o.y = f2bf(v.y); o.z = f2bf(v.z); o.w = f2bf(v.w);
        *(ushort4*)&At[row * 264 + kq] = o;
    }
    __syncthreads();

    for (int l = 0; l < 4; ++l) {
        const unsigned short* Wl = Wb + (size_t)l * wsz;
        const float* bl = (l == 0) ? b0p : (l == 1) ? b1p : (l == 2) ? b2p : b3p;
        f32x4 acc[4] = {};
        #pragma unroll
        for (int k = 0; k < 256; k += 32) {
            bf16x8 af = *(const bf16x8*)&At[l16 * 264 + k + quad * 8];
            #pragma unroll
            for (int t = 0; t < 4; ++t) {
                int n = wid * 64 + t * 16 + l16;
                bf16x8 bfr = *(const bf16x8*)(Wl + (size_t)n * 256 + k + quad * 8);
                acc[t] = __builtin_amdgcn_mfma_f32_16x16x32_bf16(af, bfr, acc[t], 0, 0, 0);
            }
        }
        __syncthreads();
        #pragma unroll
        for (int t = 0; t < 4; ++t) {
            int n = wid * 64 + t * 16 + l16;
            float bv = bl[n];
            #pragma unroll
            for (int r = 0; r < 4; ++r) {
                int m = quad * 4 + r;
                float v = acc[t][r] + bv;
                if (l < 3) {
                    At[m * 264 + n] = f2bf(fmaxf(v, 0.f));
                } else {
                    if (m0 + m < M) outQB[(size_t)(m0 + m) * 256 + n] = f2bf(v);
                }
            }
        }
        if (l < 3) __syncthreads();
    }
}

// ---------------------------------------------------------------------------
// cell_gemm8: double-buffered B staging via global_load_lds DMA (zero staging
// registers — avoids round-7's spill failure mode). One barrier per k-step;
// the DMA for slice k+1 is in flight across the whole MFMA phase of slice k,
// hiding the L2 stage latency that rounds 7/8 showed is the residual bound
// (LDS conflict/volume theories both nulled).
// Layout (rule 21: both-sides swizzle with linear DMA dest):
//   Bsm rows = 64 B (320 x 32 ushorts, no pad), 2 buffers = 40 KB.
//   LDS slot (row, sub) holds source k-chunk (sub ^ (row&3));
//   read slot = quad ^ (l16&3) -> wave's b128 read is bijective onto a
//   contiguous 1024 B region (= conflict-free baseline).
// 2 m-tiles per wave (gemm7 geometry): 128 cells/block, 512 blocks.
// ---------------------------------------------------------------------------
__global__ __launch_bounds__(256, 2) void cell_gemm8(
    const unsigned short* __restrict__ Abuf,
    const unsigned short* __restrict__ QB, const int* __restrict__ qoff,
    float* __restrict__ out, int cpb, int HW, int Qstride)
{
    __shared__ unsigned short Bsm[2][320 * 32];   // 2 x 20480 B

    const int tid = threadIdx.x;
    const int b   = blockIdx.x / cpb;
    const int c0  = (blockIdx.x - b * cpb) * 128;
    const size_t gc0 = (size_t)b * HW + c0;
    const int q0 = qoff[b];
    int qlen = qoff[b + 1] - q0; if (qlen < 1) qlen = 1;

    const int wid = tid >> 6, lane = tid & 63, quad = lane >> 4, l16 = lane & 15;

    // staging sources: thread stages chunks c = tid + i*256 (i<5, 1280 total).
    // chunk c -> (row=c>>2, sub=c&3); dest linear at c*16B; source k-chunk
    // pre-swizzled: sub ^ (row&3). rows 304..319 clamp to qlen-1 (never read).
    const unsigned short* gsrc[5];
    #pragma unroll
    for (int i = 0; i < 5; ++i) {
        int c = tid + i * 256;
        int row = c >> 2, sub = c & 3;
        int qr = row < qlen ? row : qlen - 1;
        gsrc[i] = QB + (size_t)(q0 + qr) * 256 + (sub ^ (row & 3)) * 8;
    }

    #define STAGE(s, kk)                                                      \
        { _Pragma("unroll")                                                   \
          for (int i = 0; i < 5; ++i)                                         \
              __builtin_amdgcn_global_load_lds(                               \
                  (const __attribute__((address_space(1))) unsigned int*)     \
                      (gsrc[i] + (kk)),                                       \
                  (__attribute__((address_space(3))) unsigned int*)           \
                      &Bsm[s][(tid + i * 256) * 8],                           \
                  16, 0, 0); }

    // A-fragment pointers: m-tile0 rows gc0+wid*16+l16, m-tile1 rows +64
    const unsigned short* aptr0 = Abuf + (gc0 + wid * 16 + l16) * 256 + quad * 8;
    const unsigned short* aptr1 = aptr0 + 64 * 256;
    bf16x8 afA0 = *(const bf16x8*)aptr0;
    bf16x8 afA1 = *(const bf16x8*)aptr1;
    f32x4 acc0[19] = {};
    f32x4 acc1[19] = {};

    const int rslot = (quad ^ (l16 & 3)) * 8;   // swizzled 16B slot (ushorts)

    STAGE(0, 0);
    __syncthreads();                            // drains DMA (vmcnt) + barrier

    for (int k0 = 0; k0 < 256; k0 += 32) {
        const int cur = (k0 >> 5) & 1;
        if (k0 + 32 < 256) STAGE(cur ^ 1, k0 + 32);   // fire-and-forget DMA
        int k1 = (k0 + 32) & 255;                     // wraps harmlessly
        bf16x8 afB0 = *(const bf16x8*)(aptr0 + k1);
        bf16x8 afB1 = *(const bf16x8*)(aptr1 + k1);
        #pragma unroll
        for (int t = 0; t < 19; ++t) {
            bf16x8 bfr = *(const bf16x8*)&Bsm[cur][(t * 16 + l16) * 32 + rslot];
            acc0[t] = __builtin_amdgcn_mfma_f32_16x16x32_bf16(afA0, bfr, acc0[t], 0, 0, 0);
            acc1[t] = __builtin_amdgcn_mfma_f32_16x16x32_bf16(afA1, bfr, acc1[t], 0, 0, 0);
        }
        __syncthreads();    // reads of cur done + next buffer's DMA drained
        afA0 = afB0; afA1 = afB1;
    }
    #undef STAGE

    // coalesced stores; zero-fill n >= qlen (no memset of d_out needed)
    #pragma unroll
    for (int r = 0; r < 4; ++r) {
        int m = quad * 4 + r;
        float* dst0 = out + (gc0 + wid * 16 + m) * Qstride;
        float* dst1 = out + (gc0 + 64 + wid * 16 + m) * Qstride;
        #pragma unroll
        for (int t = 0; t < 19; ++t) {
            int nq = t * 16 + l16;
            if (nq < Qstride) {
                dst0[nq] = (nq < qlen) ? acc0[t][r] : 0.f;
                dst1[nq] = (nq < qlen) ? acc1[t][r] : 0.f;
            }
        }
    }
}

extern "C" void kernel_launch(void* const* d_in, const int* in_sizes, int n_in,
                              void* d_out, int out_size, void* d_ws, size_t ws_size,
                              hipStream_t stream) {
    const float* queries = (const float*)d_in[0];
    const float* FV      = (const float*)d_in[1];
    const int*   FI      = (const int*)d_in[2];
    const int*   qoff    = (const int*)d_in[3];
    const int*   wptr    = (const int*)d_in[6];
    const float* W0 = (const float*)d_in[7];
    const float* b0 = (const float*)d_in[8];
    const float* W1 = (const float*)d_in[9];
    const float* b1 = (const float*)d_in[10];
    const float* W2 = (const float*)d_in[11];
    const float* b2 = (const float*)d_in[12];
    const float* W3 = (const float*)d_in[13];
    const float* b3 = (const float*)d_in[14];
    float* out = (float*)d_out;

    const int NQe = in_sizes[0];          // 307200
    const int NQ  = NQe / 256;            // 1200
    const int NF  = in_sizes[1] / 256;    // 65536
    const int WSZ = in_sizes[7];          // 65536
    const int B   = in_sizes[3] - 1;      // 4
    const int Q   = NQ / B;               // 300
    const int HW  = out_size / (B * Q);   // 16384
    const int NC  = B * HW;               // 65536 cells
    const int cpb = HW / 128;             // 128 blocks per batch (128-cell tiles)

    int* cnt   = (int*)d_ws;                                   // NC ints
    int* slots = cnt + (size_t)NC;                             // NC*16 ints
    unsigned short* wsW  = (unsigned short*)(slots + (size_t)NC * 16);  // 4*WSZ
    unsigned short* wsQB = wsW + (size_t)4 * WSZ;              // NQe bf16
    unsigned short* Abuf = wsQB + (size_t)NQe;                 // NC*256 bf16

    hipMemsetAsync(cnt, 0, (size_t)NC * sizeof(int), stream);

    const int nbBin = (NF + 255) / 256;
    const int nbW   = (4 * WSZ / 4 + 255) / 256;
    prep<<<nbBin + nbW, 256, 0, stream>>>(FI, wptr, cnt, slots,
                                          W0, W1, W2, W3, wsW, NF, HW, WSZ, nbBin);

    const int nbM = (NQ + 15) / 16;       // 75 mlp blocks
    const int nbG = 4096;                 // gather blocks (half-wave per cell)
    gather_mlp<<<nbM + nbG, 256, 0, stream>>>(
        queries, wsW, b0, b1, b2, b3, wsQB, NQ, WSZ,
        FV, cnt, slots, Abuf, NC, nbM, nbG);

    cell_gemm8<<<B * cpb, 256, 0, stream>>>(Abuf, wsQB, qoff, out, cpb, HW, Q);
}

// Round 10
// 192.065 us; speedup vs baseline: 1.6148x; 1.0002x over previous
//
#include <hip/hip_runtime.h>
#include <hip/hip_bf16.h>
#include <stdint.h>

typedef __attribute__((ext_vector_type(8))) short bf16x8;
typedef __attribute__((ext_vector_type(4))) float f32x4;

__device__ __forceinline__ unsigned short f2bf(float f) {
    union { float f; unsigned u; } v; v.f = f;
    unsigned u = v.u;
    u += 0x7fff + ((u >> 16) & 1);   // round-to-nearest-even
    return (unsigned short)(u >> 16);
}

// ---------------------------------------------------------------------------
// prep: blocks [0, nbBin): binner (slot claim per feature).
//       blocks [nbBin, nbBin+nbW): convert W0..W3 fp32 -> bf16 into wsW.
// ---------------------------------------------------------------------------
__global__ __launch_bounds__(256) void prep(
    const int* __restrict__ FI, const int* __restrict__ wptr,
    int* __restrict__ cnt, int* __restrict__ slots,
    const float* __restrict__ W0, const float* __restrict__ W1,
    const float* __restrict__ W2, const float* __restrict__ W3,
    unsigned short* __restrict__ wsW,
    int NF, int HW, int wsz, int nbBin)
{
    int blk = blockIdx.x;
    if (blk < nbBin) {
        int i = blk * 256 + threadIdx.x;
        if (i >= NF) return;
        int Wd = *wptr;
        int b = FI[(size_t)i * 3];
        int h = FI[(size_t)i * 3 + 1];
        int w = FI[(size_t)i * 3 + 2];
        int gc = b * HW + h * Wd + w;
        int slot = atomicAdd(&cnt[gc], 1);
        if (slot < 16) slots[(size_t)gc * 16 + slot] = i;
    } else {
        int idx = ((blk - nbBin) * 256 + threadIdx.x) * 4;
        if (idx >= 4 * wsz) return;
        int l = idx / wsz, off = idx - l * wsz;
        const float* Ws = (l == 0) ? W0 : (l == 1) ? W1 : (l == 2) ? W2 : W3;
        float4 v = *(const float4*)(Ws + off);
        ushort4 o; o.x = f2bf(v.x); o.y = f2bf(v.y); o.z = f2bf(v.z); o.w = f2bf(v.w);
        *(ushort4*)(wsW + (size_t)l * wsz + off) = o;
    }
}

// ---------------------------------------------------------------------------
// gather_mlp: blocks [0, nbM): fused 4-layer MLP.
//             blocks [nbM, nbM+nbG): cell gather, HALF-WAVE per cell.
// (round-4 verified version — best measured config)
// ---------------------------------------------------------------------------
__global__ __launch_bounds__(256) void gather_mlp(
    // mlp args
    const float* __restrict__ Qf, const unsigned short* __restrict__ Wb,
    const float* __restrict__ b0p, const float* __restrict__ b1p,
    const float* __restrict__ b2p, const float* __restrict__ b3p,
    unsigned short* __restrict__ outQB, int M, int wsz,
    // gather args
    const float* __restrict__ FV, const int* __restrict__ cnt,
    const int* __restrict__ slots, unsigned short* __restrict__ Abuf, int NC,
    int nbM, int nbG)
{
    __shared__ unsigned short At[16 * 264];
    const int tid = threadIdx.x;
    const int wid = tid >> 6, lane = tid & 63, quad = lane >> 4, l16 = lane & 15;

    if (blockIdx.x >= nbM) {
        // ------------- gather: half-wave per cell, 4 cells per wave -------------
        const int hl  = lane & 31;      // half-lane
        const int hid = lane >> 5;      // which half of the wave
        const int wg = (blockIdx.x - nbM) * 4 + wid;
        const int nw = nbG * 4;
        for (int cb = wg * 4; cb < NC; cb += nw * 4) {
            int sl = slots[(size_t)cb * 16 + lane];   // 4 cells' slots, coalesced
            #pragma unroll
            for (int i = 0; i < 2; ++i) {
                int j = i * 2 + hid;                  // this half's cell (of the 4)
                int c = cb + j;
                // wave-uniform counts for the pair of cells handled this pass
                int nA = cnt[cb + i * 2];     if (nA > 16) nA = 16;
                int nB = cnt[cb + i * 2 + 1]; if (nB > 16) nB = 16;
                int n    = hid ? nB : nA;             // own trip count
                int nmax = nA > nB ? nA : nB;         // wave-uniform bound
                float4 a0 = make_float4(0.f, 0.f, 0.f, 0.f);
                float4 a1 = a0;
                for (int s = 0; s < nmax; ++s) {
                    int f = __shfl(sl, j * 16 + s);   // ALL lanes active here
                    if (s < n) {
                        const float* src = FV + (size_t)f * 256 + hl * 4;
                        float4 v0 = *(const float4*)(src);         // cols hl*4
                        float4 v1 = *(const float4*)(src + 128);   // cols 128+hl*4
                        a0.x += v0.x; a0.y += v0.y; a0.z += v0.z; a0.w += v0.w;
                        a1.x += v1.x; a1.y += v1.y; a1.z += v1.z; a1.w += v1.w;
                    }
                }
                ushort4 o0, o1;
                o0.x = f2bf(a0.x); o0.y = f2bf(a0.y); o0.z = f2bf(a0.z); o0.w = f2bf(a0.w);
                o1.x = f2bf(a1.x); o1.y = f2bf(a1.y); o1.z = f2bf(a1.z); o1.w = f2bf(a1.w);
                unsigned short* dst = Abuf + (size_t)c * 256;
                *(ushort4*)(dst + hl * 4)       = o0;   // 256B contiguous/instr
                *(ushort4*)(dst + 128 + hl * 4) = o1;   // 256B contiguous/instr
            }
        }
        return;
    }

    // ---------------- mlp: 16 query rows x 256 N, LDS ping-pong ----------------
    const int m0 = blockIdx.x * 16;
    #pragma unroll
    for (int i = 0; i < 4; ++i) {
        int c = tid + i * 256;
        int row = c >> 6, kq = (c & 63) * 4;
        int gr = m0 + row; if (gr >= M) gr = M - 1;
        float4 v = *(const float4*)(Qf + (size_t)gr * 256 + kq);
        ushort4 o; o.x = f2bf(v.x); o.y = f2bf(v.y); o.z = f2bf(v.z); o.w = f2bf(v.w);
        *(ushort4*)&At[row * 264 + kq] = o;
    }
    __syncthreads();

    for (int l = 0; l < 4; ++l) {
        const unsigned short* Wl = Wb + (size_t)l * wsz;
        const float* bl = (l == 0) ? b0p : (l == 1) ? b1p : (l == 2) ? b2p : b3p;
        f32x4 acc[4] = {};
        #pragma unroll
        for (int k = 0; k < 256; k += 32) {
            bf16x8 af = *(const bf16x8*)&At[l16 * 264 + k + quad * 8];
            #pragma unroll
            for (int t = 0; t < 4; ++t) {
                int n = wid * 64 + t * 16 + l16;
                bf16x8 bfr = *(const bf16x8*)(Wl + (size_t)n * 256 + k + quad * 8);
                acc[t] = __builtin_amdgcn_mfma_f32_16x16x32_bf16(af, bfr, acc[t], 0, 0, 0);
            }
        }
        __syncthreads();
        #pragma unroll
        for (int t = 0; t < 4; ++t) {
            int n = wid * 64 + t * 16 + l16;
            float bv = bl[n];
            #pragma unroll
            for (int r = 0; r < 4; ++r) {
                int m = quad * 4 + r;
                float v = acc[t][r] + bv;
                if (l < 3) {
                    At[m * 264 + n] = f2bf(fmaxf(v, 0.f));
                } else {
                    if (m0 + m < M) outQB[(size_t)(m0 + m) * 256 + n] = f2bf(v);
                }
            }
        }
        if (l < 3) __syncthreads();
    }
}

// ---------------------------------------------------------------------------
// cell_gemm9: 3-buffer B staging via global_load_lds DMA with COUNTED vmcnt
// (T3+T4). Round-9's 2-buffer version drained vmcnt(0) at every __syncthreads,
// eating the DMA-latency remainder each k-step. Now: raw s_barrier (no drain)
// + per-step literal vmcnt(N) that retires only the 3-step-old DMA group.
// Schedule per step k (buf b = k%3, fully unrolled):
//   vmcnt(N) -> s_barrier -> 38 MFMA from b -> s_barrier -> STAGE(b, k+96)
// N: main=10 (2 newer DMA groups x5 + margin-2 A-prefetch loads), tail 5 / 0.
// DMA for k+96 has ~3 MFMA phases to land. LDS 3x20480 = 61.4 KB -> still
// 2 blocks/CU. Swizzle layout unchanged from gemm8 (verified).
// ---------------------------------------------------------------------------
__global__ __launch_bounds__(256, 2) void cell_gemm9(
    const unsigned short* __restrict__ Abuf,
    const unsigned short* __restrict__ QB, const int* __restrict__ qoff,
    float* __restrict__ out, int cpb, int HW, int Qstride)
{
    __shared__ unsigned short Bsm[3][320 * 32];   // 3 x 20480 B

    const int tid = threadIdx.x;
    const int b   = blockIdx.x / cpb;
    const int c0  = (blockIdx.x - b * cpb) * 128;
    const size_t gc0 = (size_t)b * HW + c0;
    const int q0 = qoff[b];
    int qlen = qoff[b + 1] - q0; if (qlen < 1) qlen = 1;

    const int wid = tid >> 6, lane = tid & 63, quad = lane >> 4, l16 = lane & 15;

    // staging sources: thread stages chunks c = tid + i*256 (i<5, 1280 total).
    // chunk c -> (row=c>>2, sub=c&3); dest linear at c*16B; source k-chunk
    // pre-swizzled: sub ^ (row&3). rows 304..319 clamp to qlen-1 (never read).
    const unsigned short* gsrc[5];
    #pragma unroll
    for (int i = 0; i < 5; ++i) {
        int c = tid + i * 256;
        int row = c >> 2, sub = c & 3;
        int qr = row < qlen ? row : qlen - 1;
        gsrc[i] = QB + (size_t)(q0 + qr) * 256 + (sub ^ (row & 3)) * 8;
    }

    #define STAGE(s, kk)                                                      \
        { _Pragma("unroll")                                                   \
          for (int i = 0; i < 5; ++i)                                         \
              __builtin_amdgcn_global_load_lds(                               \
                  (const __attribute__((address_space(1))) unsigned int*)     \
                      (gsrc[i] + (kk)),                                       \
                  (__attribute__((address_space(3))) unsigned int*)           \
                      &Bsm[s][(tid + i * 256) * 8],                           \
                  16, 0, 0); }

    // A-fragment pointers: m-tile0 rows gc0+wid*16+l16, m-tile1 rows +64
    const unsigned short* aptr0 = Abuf + (gc0 + wid * 16 + l16) * 256 + quad * 8;
    const unsigned short* aptr1 = aptr0 + 64 * 256;

    const int rslot = (quad ^ (l16 & 3)) * 8;   // swizzled 16B slot (ushorts)

    // prologue: fill 3 buffers, THEN initial A loads (A newest in vmcnt order)
    STAGE(0, 0);
    STAGE(1, 32);
    STAGE(2, 64);
    bf16x8 afA0 = *(const bf16x8*)aptr0;
    bf16x8 afA1 = *(const bf16x8*)aptr1;
    f32x4 acc0[19] = {};
    f32x4 acc1[19] = {};

    #pragma unroll
    for (int s = 0; s < 8; ++s) {
        const int k0  = s * 32;
        const int buf = s % 3;
        // retire buffer `buf`'s DMA group (3-step-old). Outstanding worst case:
        // [cur(5), +1(5), +2(5), A(2)] -> N=10 guarantees cur retired even if
        // the 2 A loads were scheduled between groups. Tail: fewer groups.
        const int N = (s < 6) ? 10 : (s == 6 ? 5 : 0);
        asm volatile("s_waitcnt vmcnt(%0)" :: "i"(N) : "memory");
        __builtin_amdgcn_s_barrier();          // all waves' DMAs for buf retired
        // A prefetch for next step (wraps harmlessly on last iter)
        const int k1 = (k0 + 32) & 255;
        bf16x8 afB0 = *(const bf16x8*)(aptr0 + k1);
        bf16x8 afB1 = *(const bf16x8*)(aptr1 + k1);
        #pragma unroll
        for (int t = 0; t < 19; ++t) {
            bf16x8 bfr = *(const bf16x8*)&Bsm[buf][(t * 16 + l16) * 32 + rslot];
            acc0[t] = __builtin_amdgcn_mfma_f32_16x16x32_bf16(afA0, bfr, acc0[t], 0, 0, 0);
            acc1[t] = __builtin_amdgcn_mfma_f32_16x16x32_bf16(afA1, bfr, acc1[t], 0, 0, 0);
        }
        __builtin_amdgcn_s_barrier();          // all waves done reading buf
        if (k0 + 96 < 256) STAGE(buf, k0 + 96);
        afA0 = afB0; afA1 = afB1;
    }
    #undef STAGE

    // coalesced stores; zero-fill n >= qlen (no memset of d_out needed)
    #pragma unroll
    for (int r = 0; r < 4; ++r) {
        int m = quad * 4 + r;
        float* dst0 = out + (gc0 + wid * 16 + m) * Qstride;
        float* dst1 = out + (gc0 + 64 + wid * 16 + m) * Qstride;
        #pragma unroll
        for (int t = 0; t < 19; ++t) {
            int nq = t * 16 + l16;
            if (nq < Qstride) {
                dst0[nq] = (nq < qlen) ? acc0[t][r] : 0.f;
                dst1[nq] = (nq < qlen) ? acc1[t][r] : 0.f;
            }
        }
    }
}

extern "C" void kernel_launch(void* const* d_in, const int* in_sizes, int n_in,
                              void* d_out, int out_size, void* d_ws, size_t ws_size,
                              hipStream_t stream) {
    const float* queries = (const float*)d_in[0];
    const float* FV      = (const float*)d_in[1];
    const int*   FI      = (const int*)d_in[2];
    const int*   qoff    = (const int*)d_in[3];
    const int*   wptr    = (const int*)d_in[6];
    const float* W0 = (const float*)d_in[7];
    const float* b0 = (const float*)d_in[8];
    const float* W1 = (const float*)d_in[9];
    const float* b1 = (const float*)d_in[10];
    const float* W2 = (const float*)d_in[11];
    const float* b2 = (const float*)d_in[12];
    const float* W3 = (const float*)d_in[13];
    const float* b3 = (const float*)d_in[14];
    float* out = (float*)d_out;

    const int NQe = in_sizes[0];          // 307200
    const int NQ  = NQe / 256;            // 1200
    const int NF  = in_sizes[1] / 256;    // 65536
    const int WSZ = in_sizes[7];          // 65536
    const int B   = in_sizes[3] - 1;      // 4
    const int Q   = NQ / B;               // 300
    const int HW  = out_size / (B * Q);   // 16384
    const int NC  = B * HW;               // 65536 cells
    const int cpb = HW / 128;             // 128 blocks per batch (128-cell tiles)

    int* cnt   = (int*)d_ws;                                   // NC ints
    int* slots = cnt + (size_t)NC;                             // NC*16 ints
    unsigned short* wsW  = (unsigned short*)(slots + (size_t)NC * 16);  // 4*WSZ
    unsigned short* wsQB = wsW + (size_t)4 * WSZ;              // NQe bf16
    unsigned short* Abuf = wsQB + (size_t)NQe;                 // NC*256 bf16

    hipMemsetAsync(cnt, 0, (size_t)NC * sizeof(int), stream);

    const int nbBin = (NF + 255) / 256;
    const int nbW   = (4 * WSZ / 4 + 255) / 256;
    prep<<<nbBin + nbW, 256, 0, stream>>>(FI, wptr, cnt, slots,
                                          W0, W1, W2, W3, wsW, NF, HW, WSZ, nbBin);

    const int nbM = (NQ + 15) / 16;       // 75 mlp blocks
    const int nbG = 4096;                 // gather blocks (half-wave per cell)
    gather_mlp<<<nbM + nbG, 256, 0, stream>>>(
        queries, wsW, b0, b1, b2, b3, wsQB, NQ, WSZ,
        FV, cnt, slots, Abuf, NC, nbM, nbG);

    cell_gemm9<<<B * cpb, 256, 0, stream>>>(Abuf, wsQB, qoff, out, cpb, HW, Q);
}